// Round 1
// baseline (74.140 us; speedup 1.0000x reference)
//
#include <hip/hip_runtime.h>

#define B 2
#define S 512
#define D 256
#define TI 2

__device__ __forceinline__ float fast_tanh(float x) {
    // tanh(x) = 1 - 2/(1 + exp(2x)); exp(2x) = exp2(x * 2*log2(e))
    // inputs bounded (|x| < ~12) -> no overflow possible in f32
    float t = __builtin_amdgcn_exp2f(x * 2.885390081777927f);
    return fmaf(-2.0f, __builtin_amdgcn_rcpf(1.0f + t), 1.0f);
}

// PT[b][e][i] = sum_d q[b][i][d] * W[e][d]
__global__ __launch_bounds__(256) void proj_kernel(const float* __restrict__ q,
                                                   const float* __restrict__ W,
                                                   float* __restrict__ PT) {
    __shared__ float qlds[4 * D];
    const int t = threadIdx.x;
    const int b = blockIdx.x / (S / 4);
    const int i0 = (blockIdx.x % (S / 4)) * 4;
    const float* qbase = q + (size_t)(b * S + i0) * D;
    for (int idx = t; idx < 4 * D; idx += 256) qlds[idx] = qbase[idx];
    __syncthreads();
    const int e = t;
    const float* wr = W + (size_t)e * D;
    float a0 = 0.f, a1 = 0.f, a2 = 0.f, a3 = 0.f;
#pragma unroll 4
    for (int d = 0; d < D; ++d) {
        float w = wr[d];
        a0 = fmaf(qlds[d], w, a0);
        a1 = fmaf(qlds[D + d], w, a1);
        a2 = fmaf(qlds[2 * D + d], w, a2);
        a3 = fmaf(qlds[3 * D + d], w, a3);
    }
    float* p = PT + (size_t)(b * D + e) * S + i0;
    *(float4*)p = make_float4(a0, a1, a2, a3);
}

__global__ __launch_bounds__(256) void atten_kernel(const float* __restrict__ PT,
                                                    const float* __restrict__ vm,
                                                    const float* __restrict__ value,
                                                    float* __restrict__ ctx,
                                                    float* __restrict__ att) {
    __shared__ float vm_lds[D];
    __shared__ float pi_lds[TI][D];
    __shared__ float a_lds[TI][S];
    __shared__ float red[TI][2][4];

    const int t = threadIdx.x;
    const int b = blockIdx.x / (S / TI);
    const int i0 = (blockIdx.x % (S / TI)) * TI;

    vm_lds[t] = vm[t];
#pragma unroll
    for (int ii = 0; ii < TI; ++ii)
        pi_lds[ii][t] = PT[(size_t)(b * D + t) * S + i0 + ii];
    __syncthreads();

    // ---- scores: s[ii][jj] over e ----
    float acc[TI][2] = {};
    const float* ptb = PT + (size_t)b * D * S;
#pragma unroll 2
    for (int e = 0; e < D; ++e) {
        float pj0 = ptb[e * S + t];
        float pj1 = ptb[e * S + t + 256];
        float v = vm_lds[e];
#pragma unroll
        for (int ii = 0; ii < TI; ++ii) {
            float pi = pi_lds[ii][e];
            acc[ii][0] = fmaf(v, fast_tanh(pj0 - pi), acc[ii][0]);
            acc[ii][1] = fmaf(v, fast_tanh(pj1 - pi), acc[ii][1]);
        }
    }

    const int lane = t & 63, wv = t >> 6;

    // ---- softmax over j (512 values spread: 2 per thread) ----
#pragma unroll
    for (int ii = 0; ii < TI; ++ii) {
        float lm = fmaxf(acc[ii][0], acc[ii][1]);
#pragma unroll
        for (int off = 32; off; off >>= 1) lm = fmaxf(lm, __shfl_xor(lm, off));
        if (lane == 0) red[ii][0][wv] = lm;
    }
    __syncthreads();
    float m[TI];
#pragma unroll
    for (int ii = 0; ii < TI; ++ii)
        m[ii] = fmaxf(fmaxf(red[ii][0][0], red[ii][0][1]),
                      fmaxf(red[ii][0][2], red[ii][0][3]));

    float p[TI][2];
#pragma unroll
    for (int ii = 0; ii < TI; ++ii) {
        p[ii][0] = __builtin_amdgcn_exp2f((acc[ii][0] - m[ii]) * 1.4426950408889634f);
        p[ii][1] = __builtin_amdgcn_exp2f((acc[ii][1] - m[ii]) * 1.4426950408889634f);
        float ls = p[ii][0] + p[ii][1];
#pragma unroll
        for (int off = 32; off; off >>= 1) ls += __shfl_xor(ls, off);
        if (lane == 0) red[ii][1][wv] = ls;
    }
    __syncthreads();
#pragma unroll
    for (int ii = 0; ii < TI; ++ii) {
        float sum = red[ii][1][0] + red[ii][1][1] + red[ii][1][2] + red[ii][1][3];
        float rinv = __builtin_amdgcn_rcpf(sum);
        float a0 = p[ii][0] * rinv;
        float a1 = p[ii][1] * rinv;
        a_lds[ii][t] = a0;
        a_lds[ii][t + 256] = a1;
        float* ar = att + (size_t)(b * S + i0 + ii) * S;
        ar[t] = a0;
        ar[t + 256] = a1;
    }
    __syncthreads();

    // ---- context[i][d] = sum_j att[i][j] * value[b][j][d]; d = t ----
    float cacc[TI] = {};
    const float* vb = value + (size_t)b * S * D + t;
#pragma unroll 4
    for (int j = 0; j < S; ++j) {
        float v = vb[(size_t)j * D];
#pragma unroll
        for (int ii = 0; ii < TI; ++ii)
            cacc[ii] = fmaf(a_lds[ii][j], v, cacc[ii]);
    }
#pragma unroll
    for (int ii = 0; ii < TI; ++ii)
        ctx[(size_t)(b * S + i0 + ii) * D + t] = cacc[ii];
}

extern "C" void kernel_launch(void* const* d_in, const int* in_sizes, int n_in,
                              void* d_out, int out_size, void* d_ws, size_t ws_size,
                              hipStream_t stream) {
    const float* q = (const float*)d_in[0];
    // d_in[1] = key (unused by the reference)
    const float* value = (const float*)d_in[2];
    const float* W = (const float*)d_in[3];
    const float* vm = (const float*)d_in[4];

    float* ctx = (float*)d_out;                  // [B,S,D]
    float* att = ctx + (size_t)B * S * D;        // [B,S,S]
    float* PT = (float*)d_ws;                    // [B,D,S] = 1 MB scratch

    proj_kernel<<<B * (S / 4), 256, 0, stream>>>(q, W, PT);
    atten_kernel<<<B * (S / TI), 256, 0, stream>>>(PT, vm, value, ctx, att);
}

// Round 2
// 63.674 us; speedup vs baseline: 1.1644x; 1.1644x over previous
//
#include <hip/hip_runtime.h>

#define B 2
#define S 512
#define D 256

#define C_2LOG2E 2.885390081777927f   // 2*log2(e)
#define LOG2E    1.4426950408889634f

// PT[b][e][i] = sum_d q[b][i][d] * W[e][d]
__global__ __launch_bounds__(256) void proj_kernel(const float* __restrict__ q,
                                                   const float* __restrict__ W,
                                                   float* __restrict__ PT) {
    __shared__ float qlds[4 * D];
    const int t = threadIdx.x;
    const int b = blockIdx.x / (S / 4);
    const int i0 = (blockIdx.x % (S / 4)) * 4;
    const float* qbase = q + (size_t)(b * S + i0) * D;
    for (int idx = t; idx < 4 * D; idx += 256) qlds[idx] = qbase[idx];
    __syncthreads();
    const int e = t;
    const float* wr = W + (size_t)e * D;
    float a0 = 0.f, a1 = 0.f, a2 = 0.f, a3 = 0.f;
#pragma unroll 4
    for (int d = 0; d < D; ++d) {
        float w = wr[d];
        a0 = fmaf(qlds[d], w, a0);
        a1 = fmaf(qlds[D + d], w, a1);
        a2 = fmaf(qlds[2 * D + d], w, a2);
        a3 = fmaf(qlds[3 * D + d], w, a3);
    }
    float* p = PT + (size_t)(b * D + e) * S + i0;
    *(float4*)p = make_float4(a0, a1, a2, a3);
}

// One block = 2 query rows (i0, i0+1); 512 threads, thread t owns column j = t.
__global__ __launch_bounds__(512) void atten_kernel(const float* __restrict__ PT,
                                                    const float* __restrict__ vm,
                                                    const float* __restrict__ value,
                                                    float* __restrict__ ctx,
                                                    float* __restrict__ att) {
    __shared__ float w2_lds[D];        // -2 * vm[e]
    __shared__ float pi_lds[2][D];     // P[i0+ii][e]
    __shared__ float a_lds[2][S];      // softmax rows for ctx phase
    __shared__ float redm[2][8];
    __shared__ float reds[2][8];

    const int t = threadIdx.x;             // 0..511 == j
    const int b = blockIdx.x / (S / 2);
    const int i0 = (blockIdx.x % (S / 2)) * 2;

    if (t < D) {
        w2_lds[t] = -2.0f * vm[t];
        const float* pr = PT + (size_t)(b * D + t) * S + i0;
        pi_lds[0][t] = pr[0];
        pi_lds[1][t] = pr[1];
    }
    __syncthreads();

    // ---- scores (shifted): acc_ii = sum_e (-2 vm[e]) / (1 + exp(2(pj-pi)))
    // softmax is shift-invariant, so the dropped constant sum_e vm[e] cancels.
    float acc0 = 0.f, acc1 = 0.f;
    const float* ptb = PT + (size_t)b * D * S + t;
#pragma unroll 8
    for (int e = 0; e < D; ++e) {
        float pj = ptb[(size_t)e * S];
        float w = w2_lds[e];
        float d0 = pj - pi_lds[0][e];
        float d1 = pj - pi_lds[1][e];
        float t0 = __builtin_amdgcn_exp2f(d0 * C_2LOG2E);
        float t1 = __builtin_amdgcn_exp2f(d1 * C_2LOG2E);
        acc0 = fmaf(w, __builtin_amdgcn_rcpf(1.0f + t0), acc0);
        acc1 = fmaf(w, __builtin_amdgcn_rcpf(1.0f + t1), acc1);
    }

    const int lane = t & 63, wv = t >> 6;

    // ---- softmax over j (one value per thread, 8 waves) ----
    float lm0 = acc0, lm1 = acc1;
#pragma unroll
    for (int off = 32; off; off >>= 1) {
        lm0 = fmaxf(lm0, __shfl_xor(lm0, off));
        lm1 = fmaxf(lm1, __shfl_xor(lm1, off));
    }
    if (lane == 0) { redm[0][wv] = lm0; redm[1][wv] = lm1; }
    __syncthreads();
    float m0 = redm[0][0], m1 = redm[1][0];
#pragma unroll
    for (int w = 1; w < 8; ++w) {
        m0 = fmaxf(m0, redm[0][w]);
        m1 = fmaxf(m1, redm[1][w]);
    }
    float p0 = __builtin_amdgcn_exp2f((acc0 - m0) * LOG2E);
    float p1 = __builtin_amdgcn_exp2f((acc1 - m1) * LOG2E);
    float ls0 = p0, ls1 = p1;
#pragma unroll
    for (int off = 32; off; off >>= 1) {
        ls0 += __shfl_xor(ls0, off);
        ls1 += __shfl_xor(ls1, off);
    }
    if (lane == 0) { reds[0][wv] = ls0; reds[1][wv] = ls1; }
    __syncthreads();
    float s0 = 0.f, s1 = 0.f;
#pragma unroll
    for (int w = 0; w < 8; ++w) { s0 += reds[0][w]; s1 += reds[1][w]; }
    float a0 = p0 * __builtin_amdgcn_rcpf(s0);
    float a1 = p1 * __builtin_amdgcn_rcpf(s1);

    a_lds[0][t] = a0;
    a_lds[1][t] = a1;
    att[(size_t)(b * S + i0) * S + t] = a0;
    att[(size_t)(b * S + i0 + 1) * S + t] = a1;
    __syncthreads();

    // ---- context: row = t>>8, d = t&255 ----
    const int row = t >> 8, d = t & 255;
    const float* vb = value + (size_t)b * S * D + d;
    const float* ar = a_lds[row];
    float cacc = 0.f;
#pragma unroll 8
    for (int j = 0; j < S; ++j)
        cacc = fmaf(ar[j], vb[(size_t)j * D], cacc);
    ctx[(size_t)(b * S + i0 + row) * D + d] = cacc;
}

extern "C" void kernel_launch(void* const* d_in, const int* in_sizes, int n_in,
                              void* d_out, int out_size, void* d_ws, size_t ws_size,
                              hipStream_t stream) {
    const float* q = (const float*)d_in[0];
    // d_in[1] = key (unused by the reference)
    const float* value = (const float*)d_in[2];
    const float* W = (const float*)d_in[3];
    const float* vm = (const float*)d_in[4];

    float* ctx = (float*)d_out;                  // [B,S,D]
    float* att = ctx + (size_t)B * S * D;        // [B,S,S]
    float* PT = (float*)d_ws;                    // [B,D,S] = 1 MB scratch

    proj_kernel<<<B * (S / 4), 256, 0, stream>>>(q, W, PT);
    atten_kernel<<<B * (S / 2), 512, 0, stream>>>(PT, vm, value, ctx, att);
}

// Round 3
// 47.759 us; speedup vs baseline: 1.5524x; 1.3332x over previous
//
#include <hip/hip_runtime.h>

#define B 2
#define S 512
#define D 256
#define C2L 2.885390081777927f    // 2*log2(e)  (prescale so tanh arg needs no mul)
#define LOG2E 1.4426950408889634f

// PT[b][e][i] = (sum_d q[b][i][d] * W[e][d]) * C2L   (and P[b][i][e] = same, row-major)
__global__ __launch_bounds__(256) void proj_kernel(const float* __restrict__ q,
                                                   const float* __restrict__ W,
                                                   float* __restrict__ PT,
                                                   float* __restrict__ P) {
    __shared__ float qlds[4 * D];
    const int t = threadIdx.x;
    const int b = blockIdx.x / (S / 4);
    const int i0 = (blockIdx.x % (S / 4)) * 4;
    const float* qbase = q + (size_t)(b * S + i0) * D;
    for (int idx = t; idx < 4 * D; idx += 256) qlds[idx] = qbase[idx];
    __syncthreads();
    const float* wr = W + (size_t)t * D;
    float a0 = 0.f, a1 = 0.f, a2 = 0.f, a3 = 0.f;
#pragma unroll 4
    for (int d = 0; d < D; ++d) {
        float w = wr[d];
        a0 = fmaf(qlds[d], w, a0);
        a1 = fmaf(qlds[D + d], w, a1);
        a2 = fmaf(qlds[2 * D + d], w, a2);
        a3 = fmaf(qlds[3 * D + d], w, a3);
    }
    a0 *= C2L; a1 *= C2L; a2 *= C2L; a3 *= C2L;
    float* p = PT + (size_t)(b * D + t) * S + i0;
    *(float4*)p = make_float4(a0, a1, a2, a3);
    if (P) {
        P[(size_t)(b * S + i0 + 0) * D + t] = a0;
        P[(size_t)(b * S + i0 + 1) * D + t] = a1;
        P[(size_t)(b * S + i0 + 2) * D + t] = a2;
        P[(size_t)(b * S + i0 + 3) * D + t] = a3;
    }
}

// Antisymmetric scores: block k owns row rA=k (j in [k,S)) and row rB=S-1-k
// (j in [rB+1,S)). Exactly S slots: t < S-k -> (rA, j=k+t); else (rB, j=t).
// Writes s[row][j] = acc and mirror s[j][row] = -acc into `sc` (the att region).
__global__ __launch_bounds__(512) void score_kernel(const float* __restrict__ PT,
                                                    const float* __restrict__ Psrc,
                                                    int rs, int es,
                                                    const float* __restrict__ vm,
                                                    float* __restrict__ sc) {
    __shared__ float vml[D], piA[D], piB[D];
    const int t = threadIdx.x;
    const int b = blockIdx.x >> 8;          // S/2 = 256 blocks per batch
    const int k = blockIdx.x & 255;
    const int rB = S - 1 - k;
    if (t < D) {
        vml[t] = vm[t];
        const size_t bo = (size_t)b * D * S;
        piA[t] = Psrc[bo + (size_t)k * rs + (size_t)t * es];
        piB[t] = Psrc[bo + (size_t)rB * rs + (size_t)t * es];
    }
    __syncthreads();

    const int segA = S - k;
    const bool inA = t < segA;
    const int row = inA ? k : rB;
    const int j = inA ? (k + t) : t;
    const float* pi = inA ? piA : piB;
    const float* pj = PT + (size_t)b * D * S + j;

    float acc = 0.f;
#pragma unroll 8
    for (int e = 0; e < D; ++e) {
        float d = pj[(size_t)e * S] - pi[e];            // already *2log2(e)
        float ex = __builtin_amdgcn_exp2f(d);           // = exp(2*(Pj-Pi))
        float th = fmaf(-2.f, __builtin_amdgcn_rcpf(1.f + ex), 1.f);  // tanh
        acc = fmaf(vml[e], th, acc);
    }
    float* sb = sc + (size_t)b * S * S;
    sb[(size_t)row * S + j] = acc;
    sb[(size_t)j * S + row] = -acc;
    if (t == 0) sb[(size_t)rB * S + rB] = 0.f;
}

// Softmax (in-place on att) + context for 4 rows per block.
__global__ __launch_bounds__(512) void softctx_kernel(float* __restrict__ att,
                                                      const float* __restrict__ value,
                                                      float* __restrict__ ctx) {
    __shared__ float a4[S][4];               // packed softmax rows: a4[j][row]
    __shared__ float part[4][8][64][4];      // ctx partials [row][js][dq]
    __shared__ float redm[4][2], reds[4][2];

    const int t = threadIdx.x;
    const int b = blockIdx.x >> 7;           // S/4 = 128 blocks per batch
    const int i0 = (blockIdx.x & 127) * 4;

    // ---- phase 1: softmax. thread -> (row = t>>7, jr = t&127), 4 j's each
    {
        const int row = t >> 7, jr = t & 127;
        const int lane = t & 63, half = (t >> 6) & 1;
        float* arow = att + (size_t)(b * S + i0 + row) * S;
        float s0 = arow[jr], s1 = arow[jr + 128], s2 = arow[jr + 256], s3 = arow[jr + 384];
        float lm = fmaxf(fmaxf(s0, s1), fmaxf(s2, s3));
#pragma unroll
        for (int off = 32; off; off >>= 1) lm = fmaxf(lm, __shfl_xor(lm, off));
        if (lane == 0) redm[row][half] = lm;
        __syncthreads();
        float m = fmaxf(redm[row][0], redm[row][1]);
        float p0 = __builtin_amdgcn_exp2f((s0 - m) * LOG2E);
        float p1 = __builtin_amdgcn_exp2f((s1 - m) * LOG2E);
        float p2 = __builtin_amdgcn_exp2f((s2 - m) * LOG2E);
        float p3 = __builtin_amdgcn_exp2f((s3 - m) * LOG2E);
        float ls = (p0 + p1) + (p2 + p3);
#pragma unroll
        for (int off = 32; off; off >>= 1) ls += __shfl_xor(ls, off);
        if (lane == 0) reds[row][half] = ls;
        __syncthreads();
        float rinv = __builtin_amdgcn_rcpf(reds[row][0] + reds[row][1]);
        p0 *= rinv; p1 *= rinv; p2 *= rinv; p3 *= rinv;
        arow[jr] = p0; arow[jr + 128] = p1; arow[jr + 256] = p2; arow[jr + 384] = p3;
        a4[jr][row] = p0; a4[jr + 128][row] = p1;
        a4[jr + 256][row] = p2; a4[jr + 384][row] = p3;
    }
    __syncthreads();

    // ---- phase 2: ctx. thread -> (dq = t&63, js = t>>6); value read once/block
    {
        const int dq = t & 63, js = t >> 6;
        float4 acc0 = {}, acc1 = {}, acc2 = {}, acc3 = {};
        const float* vb = value + (size_t)b * S * D + (size_t)dq * 4;
#pragma unroll 4
        for (int jj = 0; jj < 64; ++jj) {
            int j = js * 64 + jj;
            float4 v = *(const float4*)(vb + (size_t)j * D);
            float w0 = a4[j][0], w1 = a4[j][1], w2 = a4[j][2], w3 = a4[j][3];
            acc0.x = fmaf(w0, v.x, acc0.x); acc0.y = fmaf(w0, v.y, acc0.y);
            acc0.z = fmaf(w0, v.z, acc0.z); acc0.w = fmaf(w0, v.w, acc0.w);
            acc1.x = fmaf(w1, v.x, acc1.x); acc1.y = fmaf(w1, v.y, acc1.y);
            acc1.z = fmaf(w1, v.z, acc1.z); acc1.w = fmaf(w1, v.w, acc1.w);
            acc2.x = fmaf(w2, v.x, acc2.x); acc2.y = fmaf(w2, v.y, acc2.y);
            acc2.z = fmaf(w2, v.z, acc2.z); acc2.w = fmaf(w2, v.w, acc2.w);
            acc3.x = fmaf(w3, v.x, acc3.x); acc3.y = fmaf(w3, v.y, acc3.y);
            acc3.z = fmaf(w3, v.z, acc3.z); acc3.w = fmaf(w3, v.w, acc3.w);
        }
        *(float4*)&part[0][js][dq][0] = acc0;
        *(float4*)&part[1][js][dq][0] = acc1;
        *(float4*)&part[2][js][dq][0] = acc2;
        *(float4*)&part[3][js][dq][0] = acc3;
    }
    __syncthreads();
    if (t < 256) {
        const int row = t >> 6, dq = t & 63;
        float4 sum = {};
#pragma unroll
        for (int js = 0; js < 8; ++js) {
            float4 p = *(const float4*)&part[row][js][dq][0];
            sum.x += p.x; sum.y += p.y; sum.z += p.z; sum.w += p.w;
        }
        *(float4*)(ctx + (size_t)(b * S + i0 + row) * D + (size_t)dq * 4) = sum;
    }
}

extern "C" void kernel_launch(void* const* d_in, const int* in_sizes, int n_in,
                              void* d_out, int out_size, void* d_ws, size_t ws_size,
                              hipStream_t stream) {
    const float* q = (const float*)d_in[0];
    // d_in[1] = key (unused by the reference)
    const float* value = (const float*)d_in[2];
    const float* W = (const float*)d_in[3];
    const float* vm = (const float*)d_in[4];

    float* ctx = (float*)d_out;                    // [B,S,D]
    float* att = ctx + (size_t)B * S * D;          // [B,S,S] — holds raw scores, then softmax
    float* PT = (float*)d_ws;                      // [B,D,S], 1 MB
    const size_t ptsz = (size_t)B * D * S;
    bool haveP = ws_size >= 2u * ptsz * sizeof(float);
    float* P = haveP ? PT + ptsz : nullptr;        // [B,S,D], 1 MB (coalesced pi loads)

    proj_kernel<<<B * (S / 4), 256, 0, stream>>>(q, W, PT, P);
    if (haveP)
        score_kernel<<<B * (S / 2), 512, 0, stream>>>(PT, P, D, 1, vm, att);
    else
        score_kernel<<<B * (S / 2), 512, 0, stream>>>(PT, PT, 1, S, vm, att);
    softctx_kernel<<<B * (S / 4), 512, 0, stream>>>(att, value, ctx);
}

// Round 4
// 41.742 us; speedup vs baseline: 1.7761x; 1.1441x over previous
//
#include <hip/hip_runtime.h>

#define B 2
#define S 512
#define D 256
#define C2L 2.885390081777927f    // 2*log2(e)
#define LOG2E 1.4426950408889634f

// proj: Pr = (q @ W^T) * C2L.  Writes EJ[b][e][i] = exp2(Pr) (e-major)
// and P[b][i][e] = Pr (row-major, for the per-row factor exp2(-P)).
__global__ __launch_bounds__(256) void proj_kernel(const float* __restrict__ q,
                                                   const float* __restrict__ W,
                                                   float* __restrict__ EJ,
                                                   float* __restrict__ P) {
    __shared__ float qlds[4 * D];
    const int t = threadIdx.x;
    const int b = blockIdx.x / (S / 4);
    const int i0 = (blockIdx.x % (S / 4)) * 4;
    const float* qbase = q + (size_t)(b * S + i0) * D;
    for (int idx = t; idx < 4 * D; idx += 256) qlds[idx] = qbase[idx];
    __syncthreads();
    const float* wr = W + (size_t)t * D;
    float a0 = 0.f, a1 = 0.f, a2 = 0.f, a3 = 0.f;
#pragma unroll 4
    for (int d = 0; d < D; ++d) {
        float w = wr[d];
        a0 = fmaf(qlds[d], w, a0);
        a1 = fmaf(qlds[D + d], w, a1);
        a2 = fmaf(qlds[2 * D + d], w, a2);
        a3 = fmaf(qlds[3 * D + d], w, a3);
    }
    a0 *= C2L; a1 *= C2L; a2 *= C2L; a3 *= C2L;
    float* ej = EJ + (size_t)(b * D + t) * S + i0;
    *(float4*)ej = make_float4(__builtin_amdgcn_exp2f(a0), __builtin_amdgcn_exp2f(a1),
                               __builtin_amdgcn_exp2f(a2), __builtin_amdgcn_exp2f(a3));
    P[(size_t)(b * S + i0 + 0) * D + t] = a0;
    P[(size_t)(b * S + i0 + 1) * D + t] = a1;
    P[(size_t)(b * S + i0 + 2) * D + t] = a2;
    P[(size_t)(b * S + i0 + 3) * D + t] = a3;
}

// Triangle score kernel. Block = quad of rows: pairA=(2m,2m+1) j in (2m,512),
// pairB=(510-2m,511-2m) j in (510-2m+1... = [s] directly). Exactly 512 slots.
// 1024 threads = 512 slots x 2 e-halves; combine through LDS.
// Shifted score s' = s - c (c = sum vm) cancels in softmax; mirror = -2c - s';
// even-row diagonals written explicitly (= -c).
__global__ __launch_bounds__(1024) void score_kernel(const float* __restrict__ EJ,
                                                     const float* __restrict__ P,
                                                     const float* __restrict__ vm,
                                                     float* __restrict__ sc) {
    __shared__ float4 fA[D], fB[D];   // {exp2(-P[r0]), exp2(-P[r1]), -2*vm, 0}
    __shared__ float2 comb[2][S];
    __shared__ float cred[16];

    const int t = threadIdx.x;
    const int b = blockIdx.x >> 7;        // 128 blocks per batch
    const int m = blockIdx.x & 127;
    const int r0 = 2 * m, r1 = r0 + 1;
    const int q0 = 510 - 2 * m, q1 = q0 + 1;
    const int segA = 511 - 2 * m;

    float pc = 0.f;
    if (t < D) {
        const size_t bP = (size_t)b * S * D;
        float v = vm[t];
        pc = v;
        fA[t] = make_float4(__builtin_amdgcn_exp2f(-P[bP + (size_t)r0 * D + t]),
                            __builtin_amdgcn_exp2f(-P[bP + (size_t)r1 * D + t]),
                            -2.f * v, 0.f);
        fB[t] = make_float4(__builtin_amdgcn_exp2f(-P[bP + (size_t)q0 * D + t]),
                            __builtin_amdgcn_exp2f(-P[bP + (size_t)q1 * D + t]),
                            -2.f * v, 0.f);
    }
#pragma unroll
    for (int off = 32; off; off >>= 1) pc += __shfl_xor(pc, off);
    if ((t & 63) == 0) cred[t >> 6] = pc;
    __syncthreads();
    float c = 0.f;
#pragma unroll
    for (int wv = 0; wv < 16; ++wv) c += cred[wv];

    const int eh = t >> 9;
    const int s = t & 511;
    const bool inA = s < segA;
    const int j = inA ? (r0 + 1 + s) : s;          // pairB: j == s exactly
    const float4* ff = inA ? fA : fB;
    const float* ej = EJ + (size_t)b * D * S + j;

    float a0 = 0.f, a1 = 0.f;
    const int e0 = eh * 128;
#pragma unroll 8
    for (int e = e0; e < e0 + 128; ++e) {
        float ev = ej[(size_t)e * S];
        float4 f = ff[e];
        float x0 = ev * f.x;
        float x1 = ev * f.y;
        float y0 = 1.f + x0;
        float y1 = 1.f + x1;
        float rv = __builtin_amdgcn_rcpf(y0);      // trans pipe
        float rn = __uint_as_float(0x7EF311C3u - __float_as_uint(y1));  // VALU pipe
        rn = rn * fmaf(-y1, rn, 2.f);
        rn = rn * fmaf(-y1, rn, 2.f);
        a0 = fmaf(f.z, rv, a0);
        a1 = fmaf(f.z, rn, a1);
    }
    comb[eh][s] = make_float2(a0, a1);
    __syncthreads();

    float* sb = sc + (size_t)b * S * S;
    {
        float2 vL = comb[0][s], vH = comb[1][s];
        float d0 = vL.x + vH.x, d1 = vL.y + vH.y;
        const int rr0 = inA ? r0 : q0;
        const int rr1 = inA ? r1 : q1;
        if (eh == 0) {
            sb[(size_t)rr0 * S + j] = d0;
            sb[(size_t)rr1 * S + j] = d1;
        } else {
            *(float2*)&sb[(size_t)j * S + rr0] =
                make_float2(fmaf(-2.f, c, -d0), fmaf(-2.f, c, -d1));
        }
    }
    if (t < 2) {
        const int rr = (t == 0) ? r0 : q0;
        sb[(size_t)rr * S + rr] = -c;
    }
}

// Softmax (in-place on att) + context for 4 rows per block.
__global__ __launch_bounds__(512) void softctx_kernel(float* __restrict__ att,
                                                      const float* __restrict__ value,
                                                      float* __restrict__ ctx) {
    __shared__ float a4[S][4];
    __shared__ float part[4][8][64][4];
    __shared__ float redm[4][2], reds[4][2];

    const int t = threadIdx.x;
    const int b = blockIdx.x >> 7;
    const int i0 = (blockIdx.x & 127) * 4;

    {
        const int row = t >> 7, jr = t & 127;
        const int lane = t & 63, half = (t >> 6) & 1;
        float* arow = att + (size_t)(b * S + i0 + row) * S;
        float s0 = arow[jr], s1 = arow[jr + 128], s2 = arow[jr + 256], s3 = arow[jr + 384];
        float lm = fmaxf(fmaxf(s0, s1), fmaxf(s2, s3));
#pragma unroll
        for (int off = 32; off; off >>= 1) lm = fmaxf(lm, __shfl_xor(lm, off));
        if (lane == 0) redm[row][half] = lm;
        __syncthreads();
        float m = fmaxf(redm[row][0], redm[row][1]);
        float p0 = __builtin_amdgcn_exp2f((s0 - m) * LOG2E);
        float p1 = __builtin_amdgcn_exp2f((s1 - m) * LOG2E);
        float p2 = __builtin_amdgcn_exp2f((s2 - m) * LOG2E);
        float p3 = __builtin_amdgcn_exp2f((s3 - m) * LOG2E);
        float ls = (p0 + p1) + (p2 + p3);
#pragma unroll
        for (int off = 32; off; off >>= 1) ls += __shfl_xor(ls, off);
        if (lane == 0) reds[row][half] = ls;
        __syncthreads();
        float rinv = __builtin_amdgcn_rcpf(reds[row][0] + reds[row][1]);
        p0 *= rinv; p1 *= rinv; p2 *= rinv; p3 *= rinv;
        arow[jr] = p0; arow[jr + 128] = p1; arow[jr + 256] = p2; arow[jr + 384] = p3;
        a4[jr][row] = p0; a4[jr + 128][row] = p1;
        a4[jr + 256][row] = p2; a4[jr + 384][row] = p3;
    }
    __syncthreads();

    {
        const int dq = t & 63, js = t >> 6;
        float4 acc0 = {}, acc1 = {}, acc2 = {}, acc3 = {};
        const float* vb = value + (size_t)b * S * D + (size_t)dq * 4;
#pragma unroll 4
        for (int jj = 0; jj < 64; ++jj) {
            int j = js * 64 + jj;
            float4 v = *(const float4*)(vb + (size_t)j * D);
            float w0 = a4[j][0], w1 = a4[j][1], w2 = a4[j][2], w3 = a4[j][3];
            acc0.x = fmaf(w0, v.x, acc0.x); acc0.y = fmaf(w0, v.y, acc0.y);
            acc0.z = fmaf(w0, v.z, acc0.z); acc0.w = fmaf(w0, v.w, acc0.w);
            acc1.x = fmaf(w1, v.x, acc1.x); acc1.y = fmaf(w1, v.y, acc1.y);
            acc1.z = fmaf(w1, v.z, acc1.z); acc1.w = fmaf(w1, v.w, acc1.w);
            acc2.x = fmaf(w2, v.x, acc2.x); acc2.y = fmaf(w2, v.y, acc2.y);
            acc2.z = fmaf(w2, v.z, acc2.z); acc2.w = fmaf(w2, v.w, acc2.w);
            acc3.x = fmaf(w3, v.x, acc3.x); acc3.y = fmaf(w3, v.y, acc3.y);
            acc3.z = fmaf(w3, v.z, acc3.z); acc3.w = fmaf(w3, v.w, acc3.w);
        }
        *(float4*)&part[0][js][dq][0] = acc0;
        *(float4*)&part[1][js][dq][0] = acc1;
        *(float4*)&part[2][js][dq][0] = acc2;
        *(float4*)&part[3][js][dq][0] = acc3;
    }
    __syncthreads();
    if (t < 256) {
        const int row = t >> 6, dq = t & 63;
        float4 sum = {};
#pragma unroll
        for (int js = 0; js < 8; ++js) {
            float4 p = *(const float4*)&part[row][js][dq][0];
            sum.x += p.x; sum.y += p.y; sum.z += p.z; sum.w += p.w;
        }
        *(float4*)(ctx + (size_t)(b * S + i0 + row) * D + (size_t)dq * 4) = sum;
    }
}

extern "C" void kernel_launch(void* const* d_in, const int* in_sizes, int n_in,
                              void* d_out, int out_size, void* d_ws, size_t ws_size,
                              hipStream_t stream) {
    const float* q = (const float*)d_in[0];
    // d_in[1] = key (unused by the reference)
    const float* value = (const float*)d_in[2];
    const float* W = (const float*)d_in[3];
    const float* vm = (const float*)d_in[4];

    float* ctx = (float*)d_out;                    // [B,S,D]
    float* att = ctx + (size_t)B * S * D;          // [B,S,S]: raw scores -> softmax
    float* EJ = (float*)d_ws;                      // [B,D,S] exp2(PT), 1 MB
    float* P = EJ + (size_t)B * D * S;             // [B,S,D] prescaled proj, 1 MB

    proj_kernel<<<B * (S / 4), 256, 0, stream>>>(q, W, EJ, P);
    score_kernel<<<B * 128, 1024, 0, stream>>>(EJ, P, vm, att);
    softctx_kernel<<<B * (S / 4), 512, 0, stream>>>(att, value, ctx);
}

// Round 5
// 41.597 us; speedup vs baseline: 1.7824x; 1.0035x over previous
//
#include <hip/hip_runtime.h>

#define B 2
#define S 512
#define D 256
#define C2L 2.885390081777927f    // 2*log2(e)
#define LOG2E 1.4426950408889634f

// proj: Pt = (q @ W^T) * C2L.
//   EJ[b][e][i] = exp2(Pt)   (e-major: score kernel j-streams, coalesced)
//   EN[b][i][e] = exp2(-Pt)  (row-major: score kernel row factors, coalesced)
__global__ __launch_bounds__(256) void proj_kernel(const float* __restrict__ q,
                                                   const float* __restrict__ W,
                                                   float* __restrict__ EJ,
                                                   float* __restrict__ EN) {
    __shared__ float qlds[4 * D];
    const int t = threadIdx.x;
    const int b = blockIdx.x / (S / 4);
    const int i0 = (blockIdx.x % (S / 4)) * 4;
    const float* qbase = q + (size_t)(b * S + i0) * D;
    for (int idx = t; idx < 4 * D; idx += 256) qlds[idx] = qbase[idx];
    __syncthreads();
    const float* wr = W + (size_t)t * D;
    float a0 = 0.f, a1 = 0.f, a2 = 0.f, a3 = 0.f;
#pragma unroll 4
    for (int d = 0; d < D; ++d) {
        float w = wr[d];
        a0 = fmaf(qlds[d], w, a0);
        a1 = fmaf(qlds[D + d], w, a1);
        a2 = fmaf(qlds[2 * D + d], w, a2);
        a3 = fmaf(qlds[3 * D + d], w, a3);
    }
    a0 *= C2L; a1 *= C2L; a2 *= C2L; a3 *= C2L;
    float* ej = EJ + (size_t)(b * D + t) * S + i0;
    *(float4*)ej = make_float4(__builtin_amdgcn_exp2f(a0), __builtin_amdgcn_exp2f(a1),
                               __builtin_amdgcn_exp2f(a2), __builtin_amdgcn_exp2f(a3));
    EN[(size_t)(b * S + i0 + 0) * D + t] = __builtin_amdgcn_exp2f(-a0);
    EN[(size_t)(b * S + i0 + 1) * D + t] = __builtin_amdgcn_exp2f(-a1);
    EN[(size_t)(b * S + i0 + 2) * D + t] = __builtin_amdgcn_exp2f(-a2);
    EN[(size_t)(b * S + i0 + 3) * D + t] = __builtin_amdgcn_exp2f(-a3);
}

// Triangle scores, e-halves split ACROSS blocks (partial sums; softctx adds).
// Block: b, eh (e-half), mm in [0,128). pairA rows (2mm, 2mm+1) j in (2mm, 512);
// pairB rows (510-2mm, 511-2mm) j in [511-2mm, 512). Exactly 512 slots.
// Stored value (shifted, per half): a_h = sum_h (-2 vm) * sigma;  mirror = -a_h - 2*c_h
// (c_h = sum_h vm); diagonal = -c_h. Shifts are row-constant -> cancel in softmax.
__global__ __launch_bounds__(512, 4) void score_kernel(const float* __restrict__ EJ,
                                                       const float* __restrict__ EN,
                                                       const float* __restrict__ vm,
                                                       float* __restrict__ sc) {
    __shared__ float fpair[2][128][2];   // [pairSel][e][row01]
    __shared__ float wl[128];            // -2*vm (half)
    __shared__ float cred[8];

    const int t = threadIdx.x;
    const int bid = blockIdx.x;
    const int b = bid >> 8;
    const int m = bid & 255;
    const int eh = m & 1;
    const int mm = m >> 1;
    const int e0 = eh * 128;
    const int r0 = 2 * mm;
    const int q0 = 510 - 2 * mm;

    // stage row factors (4 rows x 128 e, all coalesced) + wl + c_h reduce
    {
        const int rr = t >> 7, el = t & 127;
        const int row = ((rr < 2) ? r0 : q0) + (rr & 1);
        fpair[rr >> 1][el][rr & 1] = EN[((size_t)b * S + row) * D + e0 + el];
    }
    float pc = 0.f;
    if (t < 128) {
        float v = vm[e0 + t];
        wl[t] = -2.f * v;
        pc = v;
    }
#pragma unroll
    for (int off = 32; off; off >>= 1) pc += __shfl_xor(pc, off);
    if ((t & 63) == 0) cred[t >> 6] = pc;
    __syncthreads();
    float ch = 0.f;
#pragma unroll
    for (int wv = 0; wv < 8; ++wv) ch += cred[wv];

    const int segA = 511 - 2 * mm;
    const bool inA = t < segA;
    const int j = inA ? (r0 + 1 + t) : t;
    const int rb0 = inA ? r0 : q0;
    const float2* fp = (const float2*)&fpair[inA ? 0 : 1][0][0];
    const float* ejp = EJ + ((size_t)b * D + e0) * S + j;

    float a0 = 0.f, a1 = 0.f;
#pragma unroll 8
    for (int el = 0; el < 128; ++el) {
        float ev = ejp[(size_t)el * S];
        float2 f = fp[el];
        float w = wl[el];
        float y0 = fmaf(ev, f.x, 1.f);
        float y1 = fmaf(ev, f.y, 1.f);
        float rv = __builtin_amdgcn_rcpf(y0);                            // trans pipe
        float rn = __uint_as_float(0x7EF311C3u - __float_as_uint(y1));   // VALU pipe
        rn = rn * fmaf(-y1, rn, 2.f);
        rn = rn * fmaf(-y1, rn, 2.f);
        a0 = fmaf(w, rv, a0);
        a1 = fmaf(w, rn, a1);
    }

    float* sb = sc + ((size_t)eh * B + b) * S * S;
    sb[(size_t)rb0 * S + j] = a0;
    sb[(size_t)(rb0 + 1) * S + j] = a1;
    *(float2*)&sb[(size_t)j * S + rb0] =
        make_float2(fmaf(-2.f, ch, -a0), fmaf(-2.f, ch, -a1));
    if (t == 0) sb[(size_t)r0 * S + r0] = -ch;
    if (t == 1) sb[(size_t)q0 * S + q0] = -ch;
}

// Softmax (sum of the two half-partials) + context for 4 rows per block.
// Writes att (d_out) exactly once, coalesced.
__global__ __launch_bounds__(512) void softctx_kernel(const float* __restrict__ sc,
                                                      const float* __restrict__ value,
                                                      float* __restrict__ att,
                                                      float* __restrict__ ctx) {
    __shared__ float a4[S][4];
    __shared__ float part[4][8][64][4];
    __shared__ float redm[4][2], reds[4][2];

    const int t = threadIdx.x;
    const int b = blockIdx.x >> 7;
    const int i0 = (blockIdx.x & 127) * 4;

    {
        const int row = t >> 7, jr = t & 127;
        const int lane = t & 63, half = (t >> 6) & 1;
        const float* s0r = sc + (size_t)(b * S + i0 + row) * S;
        const float* s1r = s0r + (size_t)B * S * S;
        float s0 = s0r[jr] + s1r[jr];
        float s1 = s0r[jr + 128] + s1r[jr + 128];
        float s2 = s0r[jr + 256] + s1r[jr + 256];
        float s3 = s0r[jr + 384] + s1r[jr + 384];
        float lm = fmaxf(fmaxf(s0, s1), fmaxf(s2, s3));
#pragma unroll
        for (int off = 32; off; off >>= 1) lm = fmaxf(lm, __shfl_xor(lm, off));
        if (lane == 0) redm[row][half] = lm;
        __syncthreads();
        float m = fmaxf(redm[row][0], redm[row][1]);
        float p0 = __builtin_amdgcn_exp2f((s0 - m) * LOG2E);
        float p1 = __builtin_amdgcn_exp2f((s1 - m) * LOG2E);
        float p2 = __builtin_amdgcn_exp2f((s2 - m) * LOG2E);
        float p3 = __builtin_amdgcn_exp2f((s3 - m) * LOG2E);
        float ls = (p0 + p1) + (p2 + p3);
#pragma unroll
        for (int off = 32; off; off >>= 1) ls += __shfl_xor(ls, off);
        if (lane == 0) reds[row][half] = ls;
        __syncthreads();
        float rinv = __builtin_amdgcn_rcpf(reds[row][0] + reds[row][1]);
        p0 *= rinv; p1 *= rinv; p2 *= rinv; p3 *= rinv;
        float* arow = att + (size_t)(b * S + i0 + row) * S;
        arow[jr] = p0; arow[jr + 128] = p1; arow[jr + 256] = p2; arow[jr + 384] = p3;
        a4[jr][row] = p0; a4[jr + 128][row] = p1;
        a4[jr + 256][row] = p2; a4[jr + 384][row] = p3;
    }
    __syncthreads();

    {
        const int dq = t & 63, js = t >> 6;
        float4 acc0 = {}, acc1 = {}, acc2 = {}, acc3 = {};
        const float* vb = value + (size_t)b * S * D + (size_t)dq * 4;
#pragma unroll 4
        for (int jj = 0; jj < 64; ++jj) {
            int j = js * 64 + jj;
            float4 v = *(const float4*)(vb + (size_t)j * D);
            float w0 = a4[j][0], w1 = a4[j][1], w2 = a4[j][2], w3 = a4[j][3];
            acc0.x = fmaf(w0, v.x, acc0.x); acc0.y = fmaf(w0, v.y, acc0.y);
            acc0.z = fmaf(w0, v.z, acc0.z); acc0.w = fmaf(w0, v.w, acc0.w);
            acc1.x = fmaf(w1, v.x, acc1.x); acc1.y = fmaf(w1, v.y, acc1.y);
            acc1.z = fmaf(w1, v.z, acc1.z); acc1.w = fmaf(w1, v.w, acc1.w);
            acc2.x = fmaf(w2, v.x, acc2.x); acc2.y = fmaf(w2, v.y, acc2.y);
            acc2.z = fmaf(w2, v.z, acc2.z); acc2.w = fmaf(w2, v.w, acc2.w);
            acc3.x = fmaf(w3, v.x, acc3.x); acc3.y = fmaf(w3, v.y, acc3.y);
            acc3.z = fmaf(w3, v.z, acc3.z); acc3.w = fmaf(w3, v.w, acc3.w);
        }
        *(float4*)&part[0][js][dq][0] = acc0;
        *(float4*)&part[1][js][dq][0] = acc1;
        *(float4*)&part[2][js][dq][0] = acc2;
        *(float4*)&part[3][js][dq][0] = acc3;
    }
    __syncthreads();
    if (t < 256) {
        const int row = t >> 6, dq = t & 63;
        float4 sum = {};
#pragma unroll
        for (int js = 0; js < 8; ++js) {
            float4 p = *(const float4*)&part[row][js][dq][0];
            sum.x += p.x; sum.y += p.y; sum.z += p.z; sum.w += p.w;
        }
        *(float4*)(ctx + (size_t)(b * S + i0 + row) * D + (size_t)dq * 4) = sum;
    }
}

extern "C" void kernel_launch(void* const* d_in, const int* in_sizes, int n_in,
                              void* d_out, int out_size, void* d_ws, size_t ws_size,
                              hipStream_t stream) {
    const float* q = (const float*)d_in[0];
    // d_in[1] = key (unused by the reference)
    const float* value = (const float*)d_in[2];
    const float* W = (const float*)d_in[3];
    const float* vm = (const float*)d_in[4];

    float* ctx = (float*)d_out;                    // [B,S,D]
    float* att = ctx + (size_t)B * S * D;          // [B,S,S] final softmax (written once)
    float* EJ = (float*)d_ws;                      // [B,D,S] exp2(Pt), 1 MB
    float* EN = EJ + (size_t)B * D * S;            // [B,S,D] exp2(-Pt), 1 MB
    float* SC = EN + (size_t)B * S * D;            // [2][B,S,S] half-partial scores, 2 MB

    proj_kernel<<<B * (S / 4), 256, 0, stream>>>(q, W, EJ, EN);
    score_kernel<<<B * 256, 512, 0, stream>>>(EJ, EN, vm, SC);
    softctx_kernel<<<B * (S / 4), 512, 0, stream>>>(SC, value, att, ctx);
}